// Round 1
// baseline (2530.800 us; speedup 1.0000x reference)
//
#include <hip/hip_runtime.h>

#define THREADS 256

__global__ void fill_k(float* __restrict__ p, float v, int n) {
    int i = blockIdx.x * blockDim.x + threadIdx.x;
    if (i < n) p[i] = v;
}

__global__ void count_k(const int* __restrict__ dst, float* __restrict__ deg, int E) {
    int e = blockIdx.x * blockDim.x + threadIdx.x;
    if (e < E) atomicAdd(&deg[dst[e]], 1.0f);
}

__global__ void dinv_k(float* __restrict__ deg, int n) {
    int i = blockIdx.x * blockDim.x + threadIdx.x;
    if (i < n) deg[i] = 1.0f / sqrtf(deg[i]);
}

// out[i][c] = bias[c] + dinv[i]^2 * h[i][c]   (self-loop term + bias init)
__global__ void agg_init_k(const float* __restrict__ h, const float* __restrict__ dinv,
                           const float* __restrict__ bias, float* __restrict__ out, int n32) {
    int idx = blockIdx.x * blockDim.x + threadIdx.x;
    if (idx >= n32) return;
    int i = idx >> 5, q = (idx & 31) * 4;
    float di = dinv[i], nn = di * di;
    float4 hv = *(const float4*)(h + (size_t)i * 128 + q);
    float4 bv = *(const float4*)(bias + q);
    float4 v = make_float4(bv.x + nn * hv.x, bv.y + nn * hv.y,
                           bv.z + nn * hv.z, bv.w + nn * hv.w);
    *(float4*)(out + (size_t)i * 128 + q) = v;
}

// out[dst] += dinv[src]*dinv[dst] * h[src]   (128 floats per edge, float4 per thread)
__global__ void scatter_k(const float* __restrict__ h, const float* __restrict__ dinv,
                          const int* __restrict__ src, const int* __restrict__ dst,
                          float* out, int E) {
    long long idx = (long long)blockIdx.x * blockDim.x + threadIdx.x;
    long long total = (long long)E * 32;
    if (idx >= total) return;
    int e = (int)(idx >> 5);
    int q = (int)(idx & 31) * 4;
    int s = src[e], d = dst[e];
    float nrm = dinv[s] * dinv[d];
    float4 hv = *(const float4*)(h + (size_t)s * 128 + q);
    float* o = out + (size_t)d * 128 + q;
    atomicAdd(o + 0, nrm * hv.x);
    atomicAdd(o + 1, nrm * hv.y);
    atomicAdd(o + 2, nrm * hv.z);
    atomicAdd(o + 3, nrm * hv.w);
}

// C[M x 128] = act( op(A)[M x 128] @ W[128 x 128] + bias + addIn )
// op(A) = optional relu on load; optional row-gather via rowIdx.
// Block tile: 64 rows x 64 cols (blockIdx.y = col half). 4x4 register tile/thread.
// NOTE: addIn may alias C (in-place add) -> no __restrict__ on those two.
__global__ __launch_bounds__(256)
void gemm128_k(const float* __restrict__ A, const int* __restrict__ rowIdx,
               const float* __restrict__ W, const float* __restrict__ bias,
               const float* addIn, float* C, int M,
               int reluA, int reluOut)
{
    __shared__ float Ws[128 * 64];   // [k][c] one 64-col half
    __shared__ float As[64 * 128];   // [r][k], XOR-swizzled in k

    const int t = threadIdx.x;
    const int cb = blockIdx.y * 64;

    // stage W half (coalesced float4)
    for (int i = t; i < 128 * 16; i += THREADS) {
        int k = i >> 4, c4 = (i & 15) * 4;
        *(float4*)(Ws + k * 64 + c4) = *(const float4*)(W + k * 128 + cb + c4);
    }

    const int c0 = (t & 15) * 4;
    const int r0 = (t >> 4) * 4;
    const int myswz = ((r0 >> 2) & 7) << 2;
    const int tilesR = (M + 63) >> 6;

    for (int rt = blockIdx.x; rt < tilesR; rt += gridDim.x) {
        const int rowBase = rt * 64;
        __syncthreads();   // protect As readers of previous tile (and Ws on 1st iter)
        // stage A tile: 64 rows x 128 k (float4 per thread, swizzled k)
        for (int i = t; i < 64 * 32; i += THREADS) {
            int r = i >> 5, q = (i & 31) * 4;
            int row = rowBase + r;
            float4 a = make_float4(0.f, 0.f, 0.f, 0.f);
            if (row < M) {
                int rr = rowIdx ? rowIdx[row] : row;
                a = *(const float4*)(A + (size_t)rr * 128 + q);
                if (reluA) {
                    a.x = fmaxf(a.x, 0.f); a.y = fmaxf(a.y, 0.f);
                    a.z = fmaxf(a.z, 0.f); a.w = fmaxf(a.w, 0.f);
                }
            }
            int swz = ((r >> 2) & 7) << 2;
            *(float4*)(As + r * 128 + (q ^ swz)) = a;
        }
        __syncthreads();

        float acc[4][4];
        #pragma unroll
        for (int i = 0; i < 4; i++)
            #pragma unroll
            for (int j = 0; j < 4; j++) acc[i][j] = 0.f;

        for (int k = 0; k < 128; k += 4) {
            float4 av[4];
            #pragma unroll
            for (int i = 0; i < 4; i++)
                av[i] = *(const float4*)(As + (r0 + i) * 128 + (k ^ myswz));
            #pragma unroll
            for (int j = 0; j < 4; j++) {
                float4 w = *(const float4*)(Ws + (k + j) * 64 + c0);
                #pragma unroll
                for (int i = 0; i < 4; i++) {
                    float a = ((const float*)&av[i])[j];
                    acc[i][0] += a * w.x;
                    acc[i][1] += a * w.y;
                    acc[i][2] += a * w.z;
                    acc[i][3] += a * w.w;
                }
            }
        }

        float4 bv = make_float4(0.f, 0.f, 0.f, 0.f);
        if (bias) bv = *(const float4*)(bias + cb + c0);
        #pragma unroll
        for (int i = 0; i < 4; i++) {
            int row = rowBase + r0 + i;
            if (row < M) {
                float4 v = make_float4(acc[i][0] + bv.x, acc[i][1] + bv.y,
                                       acc[i][2] + bv.z, acc[i][3] + bv.w);
                if (addIn) {
                    float4 ad = *(const float4*)(addIn + (size_t)row * 128 + cb + c0);
                    v.x += ad.x; v.y += ad.y; v.z += ad.z; v.w += ad.w;
                }
                if (reluOut) {
                    v.x = fmaxf(v.x, 0.f); v.y = fmaxf(v.y, 0.f);
                    v.z = fmaxf(v.z, 0.f); v.w = fmaxf(v.w, 0.f);
                }
                *(float4*)(C + (size_t)row * 128 + cb + c0) = v;
            }
        }
    }
}

// out[m] = relu( dot(Y[m], w) + b[0] ), one 64-lane wave per row
__global__ __launch_bounds__(256)
void outdot_k(const float* __restrict__ Y, const float* __restrict__ w,
              const float* __restrict__ b, float* __restrict__ out, int M)
{
    int lane = threadIdx.x & 63;
    int row = blockIdx.x * 4 + (threadIdx.x >> 6);
    if (row >= M) return;
    const float* y = Y + (size_t)row * 128;
    float v = y[lane] * w[lane] + y[lane + 64] * w[lane + 64];
    #pragma unroll
    for (int off = 32; off; off >>= 1) v += __shfl_xor(v, off, 64);
    if (lane == 0) out[row] = fmaxf(v + b[0], 0.f);
}

extern "C" void kernel_launch(void* const* d_in, const int* in_sizes, int n_in,
                              void* d_out, int out_size, void* d_ws, size_t ws_size,
                              hipStream_t stream)
{
    const float* x   = (const float*)d_in[0];
    const int*   ei  = (const int*)d_in[2];
    const int*   pei = (const int*)d_in[3];
    const float* W1  = (const float*)d_in[4];
    const float* b1  = (const float*)d_in[5];
    const float* W2  = (const float*)d_in[6];
    const float* b2  = (const float*)d_in[7];
    // d_in[8..11] = eW1/eb1/eW2/eb2 : dead w.r.t. output, skipped
    const float* pW1 = (const float*)d_in[12];
    const float* pb1 = (const float*)d_in[13];
    const float* pW2 = (const float*)d_in[14];
    const float* pb2 = (const float*)d_in[15];
    const float* pW3 = (const float*)d_in[16];
    const float* pb3 = (const float*)d_in[17];
    const float* pW4 = (const float*)d_in[18];
    const float* pb4 = (const float*)d_in[19];

    const int N  = in_sizes[0] / 128;
    const int E  = in_sizes[2] / 2;
    const int EP = in_sizes[3] / 2;

    float* ws   = (float*)d_ws;
    float* dinv = ws;
    float* bufA = ws + (((size_t)N + 256) & ~(size_t)255);
    float* bufB = bufA + (size_t)N * 128;
    float* out  = (float*)d_out;

    const int* esrc = ei;
    const int* edst = ei + E;
    const int* psrc = pei;
    const int* pdst = pei + EP;

    dim3 gB(512, 2);
    int scatterBlocks = (int)(((long long)E * 32 + 255) / 256);

    // degrees with self-loops -> dinv (in place)
    fill_k<<<(N + 255) / 256, 256, 0, stream>>>(dinv, 1.0f, N);
    count_k<<<(E + 255) / 256, 256, 0, stream>>>(edst, dinv, E);
    dinv_k<<<(N + 255) / 256, 256, 0, stream>>>(dinv, N);

    // ---- layer 0: x1(pre-relu) = D^-1/2 A_hat D^-1/2 (x@W1) + b1 ----
    gemm128_k<<<gB, THREADS, 0, stream>>>(x, nullptr, W1, nullptr, nullptr, bufA, N, 0, 0);
    agg_init_k<<<(N * 32 + 255) / 256, 256, 0, stream>>>(bufA, dinv, b1, bufB, N * 32);
    scatter_k<<<scatterBlocks, 256, 0, stream>>>(bufA, dinv, esrc, edst, bufB, E);

    // ---- layer 1: h2 = relu(x1)@W2 ; x2(pre-relu) = aggregate + b2 ----
    gemm128_k<<<gB, THREADS, 0, stream>>>(bufB, nullptr, W2, nullptr, nullptr, bufA, N, 1, 0);
    agg_init_k<<<(N * 32 + 255) / 256, 256, 0, stream>>>(bufA, dinv, b2, bufB, N * 32);
    scatter_k<<<scatterBlocks, 256, 0, stream>>>(bufA, dinv, esrc, edst, bufB, E);

    // ---- predict MLP (x2 = relu(bufB) applied on gather-load) ----
    // t   = relu(x2[psrc]) @ pW1[:128]                      -> bufA
    gemm128_k<<<gB, THREADS, 0, stream>>>(bufB, psrc, pW1, nullptr, nullptr, bufA, EP, 1, 0);
    // y1  = relu( relu(x2[pdst]) @ pW1[128:] + t + pb1 )    -> bufA (in-place add)
    gemm128_k<<<gB, THREADS, 0, stream>>>(bufB, pdst, pW1 + 128 * 128, pb1, bufA, bufA, EP, 1, 1);
    // y2  = relu(y1 @ pW2 + pb2)                            -> bufB
    gemm128_k<<<gB, THREADS, 0, stream>>>(bufA, nullptr, pW2, pb2, nullptr, bufB, EP, 0, 1);
    // y3  = relu(y2 @ pW3 + pb3)                            -> bufA
    gemm128_k<<<gB, THREADS, 0, stream>>>(bufB, nullptr, pW3, pb3, nullptr, bufA, EP, 0, 1);
    // y   = relu(y3 @ pW4 + pb4)                            -> out
    outdot_k<<<(EP + 3) / 4, 256, 0, stream>>>(bufA, pW4, pb4, out, EP);
}

// Round 2
// 662.154 us; speedup vs baseline: 3.8221x; 3.8221x over previous
//
#include <hip/hip_runtime.h>

#define THREADS 256

// ---------------- small utility kernels ----------------

__global__ void zero_int_k(int* __restrict__ p, int n) {
    int i = blockIdx.x * blockDim.x + threadIdx.x;
    if (i < n) p[i] = 0;
}

__global__ void hist_k(const int* __restrict__ dst, int* __restrict__ deg, int E) {
    int e = blockIdx.x * blockDim.x + threadIdx.x;
    if (e < E) atomicAdd(&deg[dst[e]], 1);
}

// dinv[i] = rsqrt(indeg + 1 self-loop)
__global__ void dinv_k(const int* __restrict__ deg, float* __restrict__ dinv, int n) {
    int i = blockIdx.x * blockDim.x + threadIdx.x;
    if (i < n) dinv[i] = rsqrtf((float)(deg[i] + 1));
}

// per-256-block exclusive scan; block total -> bsum
__global__ void scan1_k(const int* __restrict__ deg, int* __restrict__ rowptr,
                        int* __restrict__ bsum, int n) {
    __shared__ int s[256];
    int tid = threadIdx.x;
    int i = blockIdx.x * 256 + tid;
    int v = (i < n) ? deg[i] : 0;
    s[tid] = v;
    __syncthreads();
    #pragma unroll
    for (int off = 1; off < 256; off <<= 1) {
        int t = (tid >= off) ? s[tid - off] : 0;
        __syncthreads();
        s[tid] += t;
        __syncthreads();
    }
    if (i < n) rowptr[i] = s[tid] - v;          // exclusive within block
    if (tid == 255) bsum[blockIdx.x] = s[255];  // block total
}

// single-block exclusive scan of bsum[nb], nb <= 512
__global__ void scan2_k(int* __restrict__ bsum, int nb) {
    __shared__ int s[512];
    int tid = threadIdx.x;
    int v = (tid < nb) ? bsum[tid] : 0;
    s[tid] = v;
    __syncthreads();
    #pragma unroll
    for (int off = 1; off < 512; off <<= 1) {
        int t = (tid >= off) ? s[tid - off] : 0;
        __syncthreads();
        s[tid] += t;
        __syncthreads();
    }
    if (tid < nb) bsum[tid] = s[tid] - v;       // exclusive
}

__global__ void scan3_k(int* __restrict__ rowptr, const int* __restrict__ bsum, int n) {
    int i = blockIdx.x * blockDim.x + threadIdx.x;
    if (i < n) rowptr[i] += bsum[i >> 8];
}

__global__ void place_k(const int* __restrict__ src, const int* __restrict__ dst,
                        const int* __restrict__ rowptr, int* __restrict__ cursor,
                        int* __restrict__ csr, int E) {
    int e = blockIdx.x * blockDim.x + threadIdx.x;
    if (e < E) {
        int d = dst[e];
        int pos = rowptr[d] + atomicAdd(&cursor[d], 1);
        csr[pos] = src[e];
    }
}

// out[i][c] = bias[c] + dinv[i] * ( hp[i][c] + sum_{s in in(i)} hp[s][c] )
// hp rows already scaled by dinv[src] (GEMM epilogue). One wave per node,
// each lane owns 2 channels (float2) -> 512B coalesced row reads.
__global__ __launch_bounds__(256)
void gather_agg_k(const float* __restrict__ hp, const float* __restrict__ dinv,
                  const int* __restrict__ rowptr, const int* __restrict__ deg,
                  const int* __restrict__ csr, const float* __restrict__ bias,
                  float* __restrict__ out, int N)
{
    int lane = threadIdx.x & 63;
    int i = blockIdx.x * 4 + (threadIdx.x >> 6);
    if (i >= N) return;
    int c = lane * 2;
    float2 acc = *(const float2*)(hp + (size_t)i * 128 + c);   // self-loop term
    int beg = rowptr[i], dg = deg[i];
    for (int j = 0; j < dg; j++) {
        int s = csr[beg + j];
        float2 v = *(const float2*)(hp + (size_t)s * 128 + c);
        acc.x += v.x; acc.y += v.y;
    }
    float di = dinv[i];
    float2 bv = *(const float2*)(bias + c);
    float2 o = make_float2(bv.x + di * acc.x, bv.y + di * acc.y);
    *(float2*)(out + (size_t)i * 128 + c) = o;
}

// ---------------- GEMM ----------------
// C[M x 128] = act( op(A)[M x 128] @ W[128 x 128] * rowScale + bias + addIn )
// op(A) = optional relu on load; optional row-gather via rowIdx.
// Block tile: 64 rows x 64 cols (blockIdx.y = col half). 4x4 register tile/thread.
__global__ __launch_bounds__(256)
void gemm128_k(const float* __restrict__ A, const int* __restrict__ rowIdx,
               const float* __restrict__ W, const float* __restrict__ bias,
               const float* addIn, const float* __restrict__ rowScale,
               float* C, int M, int reluA, int reluOut)
{
    __shared__ float Ws[128 * 64];   // [k][c] one 64-col half
    __shared__ float As[64 * 128];   // [r][k], XOR-swizzled in k

    const int t = threadIdx.x;
    const int cb = blockIdx.y * 64;

    for (int i = t; i < 128 * 16; i += THREADS) {
        int k = i >> 4, c4 = (i & 15) * 4;
        *(float4*)(Ws + k * 64 + c4) = *(const float4*)(W + k * 128 + cb + c4);
    }

    const int c0 = (t & 15) * 4;
    const int r0 = (t >> 4) * 4;
    const int myswz = ((r0 >> 2) & 7) << 2;
    const int tilesR = (M + 63) >> 6;

    for (int rt = blockIdx.x; rt < tilesR; rt += gridDim.x) {
        const int rowBase = rt * 64;
        __syncthreads();
        for (int i = t; i < 64 * 32; i += THREADS) {
            int r = i >> 5, q = (i & 31) * 4;
            int row = rowBase + r;
            float4 a = make_float4(0.f, 0.f, 0.f, 0.f);
            if (row < M) {
                int rr = rowIdx ? rowIdx[row] : row;
                a = *(const float4*)(A + (size_t)rr * 128 + q);
                if (reluA) {
                    a.x = fmaxf(a.x, 0.f); a.y = fmaxf(a.y, 0.f);
                    a.z = fmaxf(a.z, 0.f); a.w = fmaxf(a.w, 0.f);
                }
            }
            int swz = ((r >> 2) & 7) << 2;
            *(float4*)(As + r * 128 + (q ^ swz)) = a;
        }
        __syncthreads();

        float acc[4][4];
        #pragma unroll
        for (int i = 0; i < 4; i++)
            #pragma unroll
            for (int j = 0; j < 4; j++) acc[i][j] = 0.f;

        for (int k = 0; k < 128; k += 4) {
            float4 av[4];
            #pragma unroll
            for (int i = 0; i < 4; i++)
                av[i] = *(const float4*)(As + (r0 + i) * 128 + (k ^ myswz));
            #pragma unroll
            for (int j = 0; j < 4; j++) {
                float4 w = *(const float4*)(Ws + (k + j) * 64 + c0);
                #pragma unroll
                for (int i = 0; i < 4; i++) {
                    float a = ((const float*)&av[i])[j];
                    acc[i][0] += a * w.x;
                    acc[i][1] += a * w.y;
                    acc[i][2] += a * w.z;
                    acc[i][3] += a * w.w;
                }
            }
        }

        float4 bv = make_float4(0.f, 0.f, 0.f, 0.f);
        if (bias) bv = *(const float4*)(bias + cb + c0);
        #pragma unroll
        for (int i = 0; i < 4; i++) {
            int row = rowBase + r0 + i;
            if (row < M) {
                float sc = rowScale ? rowScale[row] : 1.0f;
                float4 v = make_float4(acc[i][0] * sc + bv.x, acc[i][1] * sc + bv.y,
                                       acc[i][2] * sc + bv.z, acc[i][3] * sc + bv.w);
                if (addIn) {
                    float4 ad = *(const float4*)(addIn + (size_t)row * 128 + cb + c0);
                    v.x += ad.x; v.y += ad.y; v.z += ad.z; v.w += ad.w;
                }
                if (reluOut) {
                    v.x = fmaxf(v.x, 0.f); v.y = fmaxf(v.y, 0.f);
                    v.z = fmaxf(v.z, 0.f); v.w = fmaxf(v.w, 0.f);
                }
                *(float4*)(C + (size_t)row * 128 + cb + c0) = v;
            }
        }
    }
}

// out[m] = relu( dot(Y[m], w) + b[0] ), one 64-lane wave per row
__global__ __launch_bounds__(256)
void outdot_k(const float* __restrict__ Y, const float* __restrict__ w,
              const float* __restrict__ b, float* __restrict__ out, int M)
{
    int lane = threadIdx.x & 63;
    int row = blockIdx.x * 4 + (threadIdx.x >> 6);
    if (row >= M) return;
    const float* y = Y + (size_t)row * 128;
    float v = y[lane] * w[lane] + y[lane + 64] * w[lane + 64];
    #pragma unroll
    for (int off = 32; off; off >>= 1) v += __shfl_xor(v, off, 64);
    if (lane == 0) out[row] = fmaxf(v + b[0], 0.f);
}

extern "C" void kernel_launch(void* const* d_in, const int* in_sizes, int n_in,
                              void* d_out, int out_size, void* d_ws, size_t ws_size,
                              hipStream_t stream)
{
    const float* x   = (const float*)d_in[0];
    const int*   ei  = (const int*)d_in[2];
    const int*   pei = (const int*)d_in[3];
    const float* W1  = (const float*)d_in[4];
    const float* b1  = (const float*)d_in[5];
    const float* W2  = (const float*)d_in[6];
    const float* b2  = (const float*)d_in[7];
    // d_in[8..11] = edge_mlp weights: dead w.r.t. output, skipped
    const float* pW1 = (const float*)d_in[12];
    const float* pb1 = (const float*)d_in[13];
    const float* pW2 = (const float*)d_in[14];
    const float* pb2 = (const float*)d_in[15];
    const float* pW3 = (const float*)d_in[16];
    const float* pb3 = (const float*)d_in[17];
    const float* pW4 = (const float*)d_in[18];
    const float* pb4 = (const float*)d_in[19];

    const int N  = in_sizes[0] / 128;
    const int E  = in_sizes[2] / 2;
    const int EP = in_sizes[3] / 2;
    const int Npad = (N + 255) & ~255;

    float* ws   = (float*)d_ws;
    float* dinv = ws;                               // Npad floats
    float* bufA = ws + Npad;                        // N*128
    float* bufB = bufA + (size_t)N * 128;           // N*128
    int*   deg    = (int*)(bufB + (size_t)N * 128); // Npad
    int*   rowptr = deg + Npad;                     // Npad
    int*   cursor = rowptr + Npad;                  // Npad
    int*   csr    = cursor + Npad;                  // E
    int*   bsum   = csr + E;                        // 512
    float* out  = (float*)d_out;

    const int* esrc = ei;
    const int* edst = ei + E;
    const int* psrc = pei;
    const int* pdst = pei + EP;

    dim3 gB(512, 2);
    const int nb = (N + 255) / 256;        // scan blocks (<=512 assumed)
    const int gN = (N + 255) / 256;
    const int gE = (E + 255) / 256;

    // ---- CSR build (counting sort by dst) + dinv ----
    zero_int_k<<<gN, 256, 0, stream>>>(deg, N);
    zero_int_k<<<gN, 256, 0, stream>>>(cursor, N);
    hist_k<<<gE, 256, 0, stream>>>(edst, deg, E);
    dinv_k<<<gN, 256, 0, stream>>>(deg, dinv, N);
    scan1_k<<<nb, 256, 0, stream>>>(deg, rowptr, bsum, N);
    scan2_k<<<1, 512, 0, stream>>>(bsum, nb);
    scan3_k<<<gN, 256, 0, stream>>>(rowptr, bsum, N);
    place_k<<<gE, 256, 0, stream>>>(esrc, edst, rowptr, cursor, csr, E);

    // ---- layer 0: hp1 = dinv ⊙ (x@W1); x1 = dinv⊙(hp1 + Σ_in hp1) + b1 ----
    gemm128_k<<<gB, THREADS, 0, stream>>>(x, nullptr, W1, nullptr, nullptr, dinv, bufA, N, 0, 0);
    gather_agg_k<<<(N + 3) / 4, 256, 0, stream>>>(bufA, dinv, rowptr, deg, csr, b1, bufB, N);

    // ---- layer 1: hp2 = dinv ⊙ (relu(x1)@W2); x2 = dinv⊙(...) + b2 ----
    gemm128_k<<<gB, THREADS, 0, stream>>>(bufB, nullptr, W2, nullptr, nullptr, dinv, bufA, N, 1, 0);
    gather_agg_k<<<(N + 3) / 4, 256, 0, stream>>>(bufA, dinv, rowptr, deg, csr, b2, bufB, N);

    // ---- predict MLP (x2 = relu(bufB) applied on gather-load) ----
    gemm128_k<<<gB, THREADS, 0, stream>>>(bufB, psrc, pW1, nullptr, nullptr, nullptr, bufA, EP, 1, 0);
    gemm128_k<<<gB, THREADS, 0, stream>>>(bufB, pdst, pW1 + 128 * 128, pb1, bufA, nullptr, bufA, EP, 1, 1);
    gemm128_k<<<gB, THREADS, 0, stream>>>(bufA, nullptr, pW2, pb2, nullptr, nullptr, bufB, EP, 0, 1);
    gemm128_k<<<gB, THREADS, 0, stream>>>(bufB, nullptr, pW3, pb3, nullptr, nullptr, bufA, EP, 0, 1);
    outdot_k<<<(EP + 3) / 4, 256, 0, stream>>>(bufA, pW4, pb4, out, EP);
}

// Round 3
// 591.697 us; speedup vs baseline: 4.2772x; 1.1191x over previous
//
#include <hip/hip_runtime.h>

typedef __attribute__((ext_vector_type(8))) short bf16x8;
typedef __attribute__((ext_vector_type(4))) float f32x4;

// ---- split-bf16 helpers: value v ~ hi + lo, packed as (hi16<<16)|lo16 ----
__device__ __forceinline__ unsigned bfr16(float x) {            // RNE fp32->bf16 bits
    unsigned u = __float_as_uint(x);
    return (u + 0x7fffu + ((u >> 16) & 1u)) >> 16;
}
__device__ __forceinline__ unsigned pack_bf2(float v) {
    unsigned hr = bfr16(v);
    float lof = v - __uint_as_float(hr << 16);
    unsigned lr = bfr16(lof);
    return (hr << 16) | (lr & 0xffffu);
}
__device__ __forceinline__ float dec_bf2(unsigned p) {
    return __uint_as_float(p & 0xffff0000u) + __uint_as_float(p << 16);
}

// ---------------- small utility kernels ----------------

__global__ void zero_int_k(int* __restrict__ p, int n) {
    int i = blockIdx.x * blockDim.x + threadIdx.x;
    if (i < n) p[i] = 0;
}

__global__ void hist_k(const int* __restrict__ dst, int* __restrict__ deg, int E) {
    int e = blockIdx.x * blockDim.x + threadIdx.x;
    if (e < E) atomicAdd(&deg[dst[e]], 1);
}

__global__ void dinv_k(const int* __restrict__ deg, float* __restrict__ dinv, int n) {
    int i = blockIdx.x * blockDim.x + threadIdx.x;
    if (i < n) dinv[i] = rsqrtf((float)(deg[i] + 1));
}

__global__ void scan1_k(const int* __restrict__ deg, int* __restrict__ rowptr,
                        int* __restrict__ bsum, int n) {
    __shared__ int s[256];
    int tid = threadIdx.x;
    int i = blockIdx.x * 256 + tid;
    int v = (i < n) ? deg[i] : 0;
    s[tid] = v;
    __syncthreads();
    #pragma unroll
    for (int off = 1; off < 256; off <<= 1) {
        int t = (tid >= off) ? s[tid - off] : 0;
        __syncthreads();
        s[tid] += t;
        __syncthreads();
    }
    if (i < n) rowptr[i] = s[tid] - v;
    if (tid == 255) bsum[blockIdx.x] = s[255];
}

__global__ void scan2_k(int* __restrict__ bsum, int nb) {
    __shared__ int s[512];
    int tid = threadIdx.x;
    int v = (tid < nb) ? bsum[tid] : 0;
    s[tid] = v;
    __syncthreads();
    #pragma unroll
    for (int off = 1; off < 512; off <<= 1) {
        int t = (tid >= off) ? s[tid - off] : 0;
        __syncthreads();
        s[tid] += t;
        __syncthreads();
    }
    if (tid < nb) bsum[tid] = s[tid] - v;
}

__global__ void scan3_k(int* __restrict__ rowptr, const int* __restrict__ bsum, int n) {
    int i = blockIdx.x * blockDim.x + threadIdx.x;
    if (i < n) rowptr[i] += bsum[i >> 8];
}

__global__ void place_k(const int* __restrict__ src, const int* __restrict__ dst,
                        const int* __restrict__ rowptr, int* __restrict__ cursor,
                        int* __restrict__ csr, int E) {
    int e = blockIdx.x * blockDim.x + threadIdx.x;
    if (e < E) {
        int d = dst[e];
        int pos = rowptr[d] + atomicAdd(&cursor[d], 1);
        csr[pos] = src[e];
    }
}

// ---- weight prep: 128x128 fp32 -> MFMA-fragment-ordered bf16 hi[8192] + lo[8192] ----
// frag f = colHalf*16 + kt*4 + nt ; lane = ((k>>3)&3)<<4 | (n&15) ; j = k&7
__global__ void wprep_k(const float* __restrict__ W, unsigned short* __restrict__ out) {
    int idx = blockIdx.x * 256 + threadIdx.x;
    if (idx >= 16384) return;
    int k = idx >> 7, n = idx & 127;
    float v = W[k * 128 + n];
    unsigned hr = bfr16(v);
    float lof = v - __uint_as_float(hr << 16);
    unsigned lr = bfr16(lof);
    int kt = k >> 5, g = (k >> 3) & 3, j = k & 7;
    int ch = n >> 6, nt = (n >> 4) & 3, lane = (g << 4) | (n & 15);
    int f = ch * 16 + kt * 4 + nt;
    int pos = f * 512 + lane * 8 + j;
    out[pos] = (unsigned short)hr;
    out[8192 + pos] = (unsigned short)lr;
}

// out[i][c] = relu( bias[c] + dinv[i] * ( hp[i][c] + sum_{s in in(i)} hp[s][c] ) )  (packed)
__global__ __launch_bounds__(256)
void gather_agg_k(const unsigned* __restrict__ hp, const float* __restrict__ dinv,
                  const int* __restrict__ rowptr, const int* __restrict__ deg,
                  const int* __restrict__ csr, const float* __restrict__ bias,
                  unsigned* __restrict__ out, int N)
{
    int lane = threadIdx.x & 63;
    int i = blockIdx.x * 4 + (threadIdx.x >> 6);
    if (i >= N) return;
    int c = lane * 2;
    uint2 p = *(const uint2*)(hp + (size_t)i * 128 + c);
    float ax = dec_bf2(p.x), ay = dec_bf2(p.y);
    int beg = rowptr[i], dg = deg[i];
    for (int j = 0; j < dg; j++) {
        int s = csr[beg + j];
        uint2 q = *(const uint2*)(hp + (size_t)s * 128 + c);
        ax += dec_bf2(q.x); ay += dec_bf2(q.y);
    }
    float di = dinv[i];
    float ox = fmaxf(bias[c] + di * ax, 0.f);
    float oy = fmaxf(bias[c + 1] + di * ay, 0.f);
    uint2 o = make_uint2(pack_bf2(ox), pack_bf2(oy));
    *(uint2*)(out + (size_t)i * 128 + c) = o;
}

// ---------------- MFMA GEMM: C[Mx128] = act(A[Mx128] @ W + bias + addIn) ----------------
// AMODE 0: A is fp32 ; AMODE 1: A is packed split-bf16 (relu pre-applied by producer).
// W register-resident per wave (its 64-col slice, bf16 hi+lo, 128 VGPRs). No LDS.
// 8 waves: wave = strip(0..3) x colHalf(0..1); wave tile 16 rows x 64 cols.
template<int AMODE>
__global__ __launch_bounds__(512)
void mfma_gemm_k(const void* __restrict__ Asrc, const int* __restrict__ rowIdx,
                 const unsigned short* __restrict__ Wprep,
                 const float* __restrict__ bias, const float* addIn,
                 const float* __restrict__ rowScale,
                 void* Cout, int M, int outPacked, int reluOut)
{
    const int t = threadIdx.x;
    const int lane = t & 63, wave = t >> 6;
    const int ch = wave & 1, strip = wave >> 1;

    // B fragments (hi/lo), loaded once, reused for all row tiles
    bf16x8 bhi[4][4], blo[4][4];
    #pragma unroll
    for (int kt = 0; kt < 4; kt++)
        #pragma unroll
        for (int nt = 0; nt < 4; nt++) {
            int f = ch * 16 + kt * 4 + nt;
            bhi[kt][nt] = *(const bf16x8*)(Wprep + f * 512 + lane * 8);
            blo[kt][nt] = *(const bf16x8*)(Wprep + 8192 + f * 512 + lane * 8);
        }

    const int kg = (lane >> 4) * 8;
    const int tilesR = (M + 63) >> 6;

    for (int rt = blockIdx.x; rt < tilesR; rt += gridDim.x) {
        const int rowBase = rt << 6;
        const int arow = rowBase + strip * 16 + (lane & 15);
        const int rr = (arow < M) ? (rowIdx ? rowIdx[arow] : arow) : 0;

        f32x4 acc[4];
        #pragma unroll
        for (int nt = 0; nt < 4; nt++) acc[nt] = (f32x4){0.f, 0.f, 0.f, 0.f};

        #pragma unroll
        for (int kt = 0; kt < 4; kt++) {
            bf16x8 ahi, alo;
            union U8 { bf16x8 v; unsigned u[4]; };
            if (AMODE == 1) {
                const unsigned* ap = (const unsigned*)Asrc + (size_t)rr * 128 + kt * 32 + kg;
                uint4 u0 = *(const uint4*)ap;
                uint4 u1 = *(const uint4*)(ap + 4);
                U8 H, L;
                H.u[0] = __builtin_amdgcn_perm(u0.y, u0.x, 0x07060302u);
                H.u[1] = __builtin_amdgcn_perm(u0.w, u0.z, 0x07060302u);
                H.u[2] = __builtin_amdgcn_perm(u1.y, u1.x, 0x07060302u);
                H.u[3] = __builtin_amdgcn_perm(u1.w, u1.z, 0x07060302u);
                L.u[0] = __builtin_amdgcn_perm(u0.y, u0.x, 0x05040100u);
                L.u[1] = __builtin_amdgcn_perm(u0.w, u0.z, 0x05040100u);
                L.u[2] = __builtin_amdgcn_perm(u1.y, u1.x, 0x05040100u);
                L.u[3] = __builtin_amdgcn_perm(u1.w, u1.z, 0x05040100u);
                ahi = H.v; alo = L.v;
            } else {
                const float* ap = (const float*)Asrc + (size_t)rr * 128 + kt * 32 + kg;
                float4 f0 = *(const float4*)ap;
                float4 f1 = *(const float4*)(ap + 4);
                float fv[8] = {f0.x, f0.y, f0.z, f0.w, f1.x, f1.y, f1.z, f1.w};
                U8 H, L;
                #pragma unroll
                for (int p = 0; p < 4; p++) {
                    float a = fv[2 * p], b = fv[2 * p + 1];
                    unsigned ra = bfr16(a), rb = bfr16(b);
                    H.u[p] = ra | (rb << 16);
                    float la = a - __uint_as_float(ra << 16);
                    float lb = b - __uint_as_float(rb << 16);
                    L.u[p] = bfr16(la) | (bfr16(lb) << 16);
                }
                ahi = H.v; alo = L.v;
            }
            #pragma unroll
            for (int nt = 0; nt < 4; nt++) {
                acc[nt] = __builtin_amdgcn_mfma_f32_16x16x32_bf16(ahi, bhi[kt][nt], acc[nt], 0, 0, 0);
                acc[nt] = __builtin_amdgcn_mfma_f32_16x16x32_bf16(ahi, blo[kt][nt], acc[nt], 0, 0, 0);
                acc[nt] = __builtin_amdgcn_mfma_f32_16x16x32_bf16(alo, bhi[kt][nt], acc[nt], 0, 0, 0);
            }
        }

        // epilogue: D row = (lane>>4)*4 + reg, col = ch*64 + nt*16 + (lane&15)
        const int colBase = ch * 64 + (lane & 15);
        const int orow0 = rowBase + strip * 16 + ((lane >> 4) << 2);
        #pragma unroll
        for (int nt = 0; nt < 4; nt++) {
            int c = colBase + nt * 16;
            float bv = bias ? bias[c] : 0.f;
            #pragma unroll
            for (int r = 0; r < 4; r++) {
                int row = orow0 + r;
                if (row < M) {
                    float v = acc[nt][r];
                    if (rowScale) v *= rowScale[row];
                    v += bv;
                    if (addIn) v += addIn[(size_t)row * 128 + c];
                    if (reluOut) v = fmaxf(v, 0.f);
                    if (outPacked) ((unsigned*)Cout)[(size_t)row * 128 + c] = pack_bf2(v);
                    else           ((float*)Cout)[(size_t)row * 128 + c] = v;
                }
            }
        }
    }
}

// out[m] = relu( dot(Y[m], w) + b[0] ), Y packed; one wave per row
__global__ __launch_bounds__(256)
void outdot_k(const unsigned* __restrict__ Y, const float* __restrict__ w,
              const float* __restrict__ b, float* __restrict__ out, int M)
{
    int lane = threadIdx.x & 63;
    int row = blockIdx.x * 4 + (threadIdx.x >> 6);
    if (row >= M) return;
    const unsigned* y = Y + (size_t)row * 128;
    float v = dec_bf2(y[lane]) * w[lane] + dec_bf2(y[lane + 64]) * w[lane + 64];
    #pragma unroll
    for (int off = 32; off; off >>= 1) v += __shfl_xor(v, off, 64);
    if (lane == 0) out[row] = fmaxf(v + b[0], 0.f);
}

extern "C" void kernel_launch(void* const* d_in, const int* in_sizes, int n_in,
                              void* d_out, int out_size, void* d_ws, size_t ws_size,
                              hipStream_t stream)
{
    const float* x   = (const float*)d_in[0];
    const int*   ei  = (const int*)d_in[2];
    const int*   pei = (const int*)d_in[3];
    const float* W1  = (const float*)d_in[4];
    const float* b1  = (const float*)d_in[5];
    const float* W2  = (const float*)d_in[6];
    const float* b2  = (const float*)d_in[7];
    // d_in[8..11] = edge_mlp weights: dead w.r.t. output, skipped
    const float* pW1 = (const float*)d_in[12];
    const float* pb1 = (const float*)d_in[13];
    const float* pW2 = (const float*)d_in[14];
    const float* pb2 = (const float*)d_in[15];
    const float* pW3 = (const float*)d_in[16];
    const float* pb3 = (const float*)d_in[17];
    const float* pW4 = (const float*)d_in[18];
    const float* pb4 = (const float*)d_in[19];

    const int N  = in_sizes[0] / 128;
    const int E  = in_sizes[2] / 2;
    const int EP = in_sizes[3] / 2;
    const int Npad = (N + 255) & ~255;

    float*    ws     = (float*)d_ws;
    float*    dinv   = ws;                                  // Npad
    unsigned* bufA   = (unsigned*)(ws + Npad);              // N*128 (u32/f32 views)
    unsigned* bufB   = bufA + (size_t)N * 128;              // N*128
    int*      deg    = (int*)(bufB + (size_t)N * 128);      // Npad
    int*      rowptr = deg + Npad;                          // Npad
    int*      cursor = rowptr + Npad;                       // Npad
    int*      csr    = cursor + Npad;                       // E
    int*      bsum   = csr + E;                             // 512
    // weight-prep area, 16B aligned
    size_t wpOff = ((size_t)(bsum + 512) + 15) & ~(size_t)15;
    unsigned short* wp = (unsigned short*)wpOff;
    unsigned short* W1p  = wp;
    unsigned short* W2p  = wp + 16384;
    unsigned short* P1Ap = wp + 2 * 16384;
    unsigned short* P1Bp = wp + 3 * 16384;
    unsigned short* P2p  = wp + 4 * 16384;
    unsigned short* P3p  = wp + 5 * 16384;
    float* out = (float*)d_out;

    const int* esrc = ei;
    const int* edst = ei + E;
    const int* psrc = pei;
    const int* pdst = pei + EP;

    const int nb = (N + 255) / 256;
    const int gN = (N + 255) / 256;
    const int gE = (E + 255) / 256;

    // ---- CSR build (counting sort by dst) + dinv ----
    zero_int_k<<<gN, 256, 0, stream>>>(deg, N);
    zero_int_k<<<gN, 256, 0, stream>>>(cursor, N);
    hist_k<<<gE, 256, 0, stream>>>(edst, deg, E);
    dinv_k<<<gN, 256, 0, stream>>>(deg, dinv, N);
    scan1_k<<<nb, 256, 0, stream>>>(deg, rowptr, bsum, N);
    scan2_k<<<1, 512, 0, stream>>>(bsum, nb);
    scan3_k<<<gN, 256, 0, stream>>>(rowptr, bsum, N);
    place_k<<<gE, 256, 0, stream>>>(esrc, edst, rowptr, cursor, csr, E);

    // ---- weight prep (frag-ordered split-bf16) ----
    wprep_k<<<64, 256, 0, stream>>>(W1, W1p);
    wprep_k<<<64, 256, 0, stream>>>(W2, W2p);
    wprep_k<<<64, 256, 0, stream>>>(pW1, P1Ap);
    wprep_k<<<64, 256, 0, stream>>>(pW1 + 128 * 128, P1Bp);
    wprep_k<<<64, 256, 0, stream>>>(pW2, P2p);
    wprep_k<<<64, 256, 0, stream>>>(pW3, P3p);

    // ---- layer 0: hp1 = dinv ⊙ (x@W1) [packed]; x1r = relu(agg + b1) [packed] ----
    mfma_gemm_k<0><<<512, 512, 0, stream>>>(x, nullptr, W1p, nullptr, nullptr, dinv,
                                            bufA, N, 1, 0);
    gather_agg_k<<<(N + 3) / 4, 256, 0, stream>>>(bufA, dinv, rowptr, deg, csr, b1, bufB, N);

    // ---- layer 1 ----
    mfma_gemm_k<1><<<512, 512, 0, stream>>>(bufB, nullptr, W2p, nullptr, nullptr, dinv,
                                            bufA, N, 1, 0);
    gather_agg_k<<<(N + 3) / 4, 256, 0, stream>>>(bufA, dinv, rowptr, deg, csr, b2, bufB, N);

    // ---- predict MLP (x2r = bufB packed) ----
    // t = x2r[psrc] @ pW1a          -> bufA (fp32)
    mfma_gemm_k<1><<<512, 512, 0, stream>>>(bufB, psrc, P1Ap, nullptr, nullptr, nullptr,
                                            bufA, EP, 0, 0);
    // y1 = relu(x2r[pdst] @ pW1b + t + pb1) -> bufA (packed, aliases addIn: same-thread RMW)
    mfma_gemm_k<1><<<512, 512, 0, stream>>>(bufB, pdst, P1Bp, pb1, (const float*)bufA, nullptr,
                                            bufA, EP, 1, 1);
    // y2 = relu(y1 @ pW2 + pb2)     -> bufB
    mfma_gemm_k<1><<<512, 512, 0, stream>>>(bufA, nullptr, P2p, pb2, nullptr, nullptr,
                                            bufB, EP, 1, 1);
    // y3 = relu(y2 @ pW3 + pb3)     -> bufA
    mfma_gemm_k<1><<<512, 512, 0, stream>>>(bufB, nullptr, P3p, pb3, nullptr, nullptr,
                                            bufA, EP, 1, 1);
    // y  = relu(y3 . pW4 + pb4)     -> out
    outdot_k<<<(EP + 3) / 4, 256, 0, stream>>>(bufA, pW4, pb4, out, EP);
}

// Round 4
// 359.615 us; speedup vs baseline: 7.0375x; 1.6454x over previous
//
#include <hip/hip_runtime.h>

typedef __attribute__((ext_vector_type(8))) short bf16x8;
typedef __attribute__((ext_vector_type(4))) float f32x4;

// ---- split-bf16 helpers: value v ~ hi + lo, packed as (hi16<<16)|lo16 ----
__device__ __forceinline__ unsigned bfr16(float x) {            // RNE fp32->bf16 bits
    unsigned u = __float_as_uint(x);
    return (u + 0x7fffu + ((u >> 16) & 1u)) >> 16;
}
__device__ __forceinline__ unsigned pack_bf2(float v) {
    unsigned hr = bfr16(v);
    float lof = v - __uint_as_float(hr << 16);
    unsigned lr = bfr16(lof);
    return (hr << 16) | (lr & 0xffffu);
}
__device__ __forceinline__ float dec_bf2(unsigned p) {
    return __uint_as_float(p & 0xffff0000u) + __uint_as_float(p << 16);
}

// A-fragment from 8 consecutive packed u32 (works for global or LDS pointers)
union U8 { bf16x8 v; unsigned u[4]; };
__device__ __forceinline__ void afrag_packed(const unsigned* ap, bf16x8& ahi, bf16x8& alo) {
    uint4 u0 = *(const uint4*)ap;
    uint4 u1 = *(const uint4*)(ap + 4);
    U8 H, L;
    H.u[0] = __builtin_amdgcn_perm(u0.y, u0.x, 0x07060302u);
    H.u[1] = __builtin_amdgcn_perm(u0.w, u0.z, 0x07060302u);
    H.u[2] = __builtin_amdgcn_perm(u1.y, u1.x, 0x07060302u);
    H.u[3] = __builtin_amdgcn_perm(u1.w, u1.z, 0x07060302u);
    L.u[0] = __builtin_amdgcn_perm(u0.y, u0.x, 0x05040100u);
    L.u[1] = __builtin_amdgcn_perm(u0.w, u0.z, 0x05040100u);
    L.u[2] = __builtin_amdgcn_perm(u1.y, u1.x, 0x05040100u);
    L.u[3] = __builtin_amdgcn_perm(u1.w, u1.z, 0x05040100u);
    ahi = H.v; alo = L.v;
}

// B fragment pair from frag-ordered weight planes (hi at 0, lo at +16384 u16)
__device__ __forceinline__ void bfrag(const unsigned short* Wp, int f, int lane,
                                      bf16x8& bhi, bf16x8& blo) {
    bhi = *(const bf16x8*)(Wp + f * 512 + lane * 8);
    blo = *(const bf16x8*)(Wp + 16384 + f * 512 + lane * 8);
}

#define MFMA3(accv, ahi, alo, bhi, blo)                                              \
    accv = __builtin_amdgcn_mfma_f32_16x16x32_bf16(ahi, bhi, accv, 0, 0, 0);         \
    accv = __builtin_amdgcn_mfma_f32_16x16x32_bf16(ahi, blo, accv, 0, 0, 0);         \
    accv = __builtin_amdgcn_mfma_f32_16x16x32_bf16(alo, bhi, accv, 0, 0, 0);

// ---------------- CSR build ----------------

__global__ void zero2_k(int* __restrict__ a, int* __restrict__ b, int n) {
    int i = blockIdx.x * blockDim.x + threadIdx.x;
    if (i < n) { a[i] = 0; b[i] = 0; }
}

__global__ void hist_k(const int* __restrict__ dst, int* __restrict__ deg, int E) {
    int e = blockIdx.x * blockDim.x + threadIdx.x;
    if (e < E) atomicAdd(&deg[dst[e]], 1);
}

// per-256-block exclusive scan; block total -> bsum; also dinv = rsqrt(deg+1)
__global__ void scan1_k(const int* __restrict__ deg, int* __restrict__ rowptr,
                        int* __restrict__ bsum, float* __restrict__ dinv, int n) {
    __shared__ int s[256];
    int tid = threadIdx.x;
    int i = blockIdx.x * 256 + tid;
    int v = (i < n) ? deg[i] : 0;
    s[tid] = v;
    __syncthreads();
    #pragma unroll
    for (int off = 1; off < 256; off <<= 1) {
        int t = (tid >= off) ? s[tid - off] : 0;
        __syncthreads();
        s[tid] += t;
        __syncthreads();
    }
    if (i < n) {
        rowptr[i] = s[tid] - v;
        dinv[i] = rsqrtf((float)(v + 1));
    }
    if (tid == 255) bsum[blockIdx.x] = s[255];
}

__global__ void scan2_k(int* __restrict__ bsum, int nb) {
    __shared__ int s[512];
    int tid = threadIdx.x;
    int v = (tid < nb) ? bsum[tid] : 0;
    s[tid] = v;
    __syncthreads();
    #pragma unroll
    for (int off = 1; off < 512; off <<= 1) {
        int t = (tid >= off) ? s[tid - off] : 0;
        __syncthreads();
        s[tid] += t;
        __syncthreads();
    }
    if (tid < nb) bsum[tid] = s[tid] - v;
}

__global__ void scan3_k(int* __restrict__ rowptr, const int* __restrict__ bsum, int n) {
    int i = blockIdx.x * blockDim.x + threadIdx.x;
    if (i < n) rowptr[i] += bsum[i >> 8];
}

__global__ void place_k(const int* __restrict__ src, const int* __restrict__ dst,
                        const int* __restrict__ rowptr, int* __restrict__ cursor,
                        int* __restrict__ csr, int E) {
    int e = blockIdx.x * blockDim.x + threadIdx.x;
    if (e < E) {
        int d = dst[e];
        int pos = rowptr[d] + atomicAdd(&cursor[d], 1);
        csr[pos] = src[e];
    }
}

// ---- weight prep: 128x128 fp32 -> frag-ordered split-bf16; hi plane [0,16384), lo [16384,32768)
// frag f = kt*8 + nt ; lane = ((k>>3)&3)<<4 | (n&15) ; j = k&7
__global__ void wprep6_k(const float* __restrict__ s0, const float* __restrict__ s1,
                         const float* __restrict__ s2, const float* __restrict__ s3,
                         const float* __restrict__ s4, const float* __restrict__ s5,
                         unsigned short* __restrict__ dstBase) {
    const float* W;
    switch (blockIdx.y) {
        case 0: W = s0; break; case 1: W = s1; break; case 2: W = s2; break;
        case 3: W = s3; break; case 4: W = s4; break; default: W = s5; break;
    }
    unsigned short* out = dstBase + (size_t)blockIdx.y * 32768;
    int idx = blockIdx.x * 256 + threadIdx.x;
    if (idx >= 16384) return;
    int k = idx >> 7, n = idx & 127;
    float v = W[k * 128 + n];
    unsigned hr = bfr16(v);
    float lof = v - __uint_as_float(hr << 16);
    unsigned lr = bfr16(lof);
    int kt = k >> 5, g = (k >> 3) & 3, j = k & 7;
    int nt = n >> 4, lane = (g << 4) | (n & 15);
    int pos = (kt * 8 + nt) * 512 + lane * 8 + j;
    out[pos] = (unsigned short)hr;
    out[16384 + pos] = (unsigned short)lr;
}

// ---- gather aggregate: out[i] = relu(bias + dinv[i]*(hp[i] + sum_in hp[s])), packed.
// 2 nodes per wave; 32 lanes x uint4 (16B) per node; 2-way unrolled neighbor loop.
__global__ __launch_bounds__(256)
void gather2_k(const unsigned* __restrict__ hp, const float* __restrict__ dinv,
               const int* __restrict__ rowptr, const int* __restrict__ deg,
               const int* __restrict__ csr, const float* __restrict__ bias,
               unsigned* __restrict__ out, int N)
{
    int tid = threadIdx.x;
    int lane = tid & 63;
    int sub = lane >> 5;
    int i = blockIdx.x * 8 + (tid >> 6) * 2 + sub;
    if (i >= N) return;
    int c4 = (lane & 31) * 4;
    uint4 p = *(const uint4*)(hp + (size_t)i * 128 + c4);
    float a0 = dec_bf2(p.x), a1 = dec_bf2(p.y), a2 = dec_bf2(p.z), a3 = dec_bf2(p.w);
    int beg = rowptr[i], dg = deg[i];
    int j = 0;
    for (; j + 1 < dg; j += 2) {
        int s0 = csr[beg + j], s1 = csr[beg + j + 1];
        uint4 q0 = *(const uint4*)(hp + (size_t)s0 * 128 + c4);
        uint4 q1 = *(const uint4*)(hp + (size_t)s1 * 128 + c4);
        a0 += dec_bf2(q0.x) + dec_bf2(q1.x);
        a1 += dec_bf2(q0.y) + dec_bf2(q1.y);
        a2 += dec_bf2(q0.z) + dec_bf2(q1.z);
        a3 += dec_bf2(q0.w) + dec_bf2(q1.w);
    }
    if (j < dg) {
        int s0 = csr[beg + j];
        uint4 q0 = *(const uint4*)(hp + (size_t)s0 * 128 + c4);
        a0 += dec_bf2(q0.x); a1 += dec_bf2(q0.y); a2 += dec_bf2(q0.z); a3 += dec_bf2(q0.w);
    }
    float di = dinv[i];
    float4 bv = *(const float4*)(bias + c4);
    uint4 o;
    o.x = pack_bf2(fmaxf(bv.x + di * a0, 0.f));
    o.y = pack_bf2(fmaxf(bv.y + di * a1, 0.f));
    o.z = pack_bf2(fmaxf(bv.z + di * a2, 0.f));
    o.w = pack_bf2(fmaxf(bv.w + di * a3, 0.f));
    *(uint4*)(out + (size_t)i * 128 + c4) = o;
}

// ---- layer GEMM: C = dinv-row-scaled (A @ W), packed out. 8 waves x 16-row tiles.
template<int AMODE>   // 0: A fp32 ; 1: A packed split-bf16
__global__ __launch_bounds__(512)
void rowgemm_k(const void* __restrict__ Asrc, const unsigned short* __restrict__ Wp,
               const float* __restrict__ rowScale, unsigned* __restrict__ Cout, int M)
{
    const int t = threadIdx.x, lane = t & 63, wave = t >> 6;
    const int base = blockIdx.x * 128 + wave * 16;
    const int c = lane & 15, g = lane >> 4, kg = g * 8;
    const int arow = base + c;
    const int rowc = (arow < M) ? arow : (M - 1);

    f32x4 acc[8];
    #pragma unroll
    for (int nt = 0; nt < 8; nt++) acc[nt] = (f32x4){0.f, 0.f, 0.f, 0.f};

    #pragma unroll
    for (int kt = 0; kt < 4; kt++) {
        bf16x8 ahi, alo;
        if (AMODE == 1) {
            afrag_packed((const unsigned*)Asrc + (size_t)rowc * 128 + kt * 32 + kg, ahi, alo);
        } else {
            const float* fp = (const float*)Asrc + (size_t)rowc * 128 + kt * 32 + kg;
            float4 f0 = *(const float4*)fp;
            float4 f1 = *(const float4*)(fp + 4);
            float fv[8] = {f0.x, f0.y, f0.z, f0.w, f1.x, f1.y, f1.z, f1.w};
            U8 H, L;
            #pragma unroll
            for (int p = 0; p < 4; p++) {
                float a = fv[2 * p], b = fv[2 * p + 1];
                unsigned ra = bfr16(a), rb = bfr16(b);
                H.u[p] = ra | (rb << 16);
                float la = a - __uint_as_float(ra << 16);
                float lb = b - __uint_as_float(rb << 16);
                L.u[p] = bfr16(la) | (bfr16(lb) << 16);
            }
            ahi = H.v; alo = L.v;
        }
        #pragma unroll
        for (int nt = 0; nt < 8; nt++) {
            bf16x8 bhi, blo;
            bfrag(Wp, kt * 8 + nt, lane, bhi, blo);
            MFMA3(acc[nt], ahi, alo, bhi, blo);
        }
    }

    // epilogue: C row = base + g*4 + r, col = nt*16 + c
    #pragma unroll
    for (int r = 0; r < 4; r++) {
        int row = base + g * 4 + r;
        if (row < M) {
            float sc = rowScale[row];
            #pragma unroll
            for (int nt = 0; nt < 8; nt++)
                Cout[(size_t)row * 128 + nt * 16 + c] = pack_bf2(acc[nt][r] * sc);
        }
    }
}

// ---- layer transition inside mlp_k: accOut = (relu(accIn + bias)) @ Wp via LDS repack ----
__device__ __forceinline__ void layer_step(const f32x4* accIn, const float* __restrict__ bias,
                                           const unsigned short* __restrict__ Wp,
                                           f32x4* accOut, unsigned* sbuf, int lane)
{
    const int c = lane & 15, g = lane >> 4;
    #pragma unroll
    for (int kt = 0; kt < 4; kt++) {
        // stage 32 cols (nt = 2kt, 2kt+1) of relu(accIn+bias), XOR-swizzled by row&3
        #pragma unroll
        for (int ntL = 0; ntL < 2; ntL++) {
            const int nt = kt * 2 + ntL;
            float bv = bias[nt * 16 + c];
            #pragma unroll
            for (int r = 0; r < 4; r++) {
                float v = fmaxf(accIn[nt][r] + bv, 0.f);
                sbuf[(g * 4 + r) * 32 + ((ntL * 16 + c) ^ (r << 3))] = pack_bf2(v);
            }
        }
        asm volatile("s_waitcnt lgkmcnt(0)" ::: "memory");   // wave-local write->read fence
        __builtin_amdgcn_sched_barrier(0);
        bf16x8 ahi, alo;
        afrag_packed(sbuf + c * 32 + ((g ^ (c & 3)) << 3), ahi, alo);  // row=lane&15, kgrp=lane>>4
        #pragma unroll
        for (int nt = 0; nt < 8; nt++) {
            bf16x8 bhi, blo;
            bfrag(Wp, kt * 8 + nt, lane, bhi, blo);
            MFMA3(accOut[nt], ahi, alo, bhi, blo);
        }
    }
}

// ---- fused predict MLP: gather xi/xj -> y1 -> y2 -> y3 -> dot -> out ----
__global__ __launch_bounds__(512)
void mlp_k(const unsigned* __restrict__ X, const int* __restrict__ psrc, const int* __restrict__ pdst,
           const unsigned short* __restrict__ W1a, const unsigned short* __restrict__ W1b,
           const float* __restrict__ b1, const unsigned short* __restrict__ W2p,
           const float* __restrict__ b2, const unsigned short* __restrict__ W3p,
           const float* __restrict__ b3, const float* __restrict__ w4,
           const float* __restrict__ b4p, float* __restrict__ out, int M)
{
    __shared__ unsigned stg[8][512];   // 2KB per wave
    const int t = threadIdx.x, lane = t & 63, wave = t >> 6;
    const int base = blockIdx.x * 128 + wave * 16;
    const int c = lane & 15, g = lane >> 4, kg = g * 8;
    const int arow = base + c;
    const int rowc = (arow < M) ? arow : (M - 1);
    const int si = psrc[rowc], sj = pdst[rowc];

    f32x4 acc1[8];
    #pragma unroll
    for (int nt = 0; nt < 8; nt++) acc1[nt] = (f32x4){0.f, 0.f, 0.f, 0.f};

    // layer 1: y1acc = xi@W1a + xj@W1b
    #pragma unroll
    for (int part = 0; part < 2; part++) {
        const unsigned* xr = X + (size_t)(part ? sj : si) * 128;
        const unsigned short* Wp = part ? W1b : W1a;
        #pragma unroll
        for (int kt = 0; kt < 4; kt++) {
            bf16x8 ahi, alo;
            afrag_packed(xr + kt * 32 + kg, ahi, alo);
            #pragma unroll
            for (int nt = 0; nt < 8; nt++) {
                bf16x8 bhi, blo;
                bfrag(Wp, kt * 8 + nt, lane, bhi, blo);
                MFMA3(acc1[nt], ahi, alo, bhi, blo);
            }
        }
    }

    f32x4 acc2[8];
    #pragma unroll
    for (int nt = 0; nt < 8; nt++) acc2[nt] = (f32x4){0.f, 0.f, 0.f, 0.f};
    layer_step(acc1, b1, W2p, acc2, &stg[wave][0], lane);   // y2acc = relu(y1)@W2

    f32x4 acc3[8];
    #pragma unroll
    for (int nt = 0; nt < 8; nt++) acc3[nt] = (f32x4){0.f, 0.f, 0.f, 0.f};
    layer_step(acc2, b2, W3p, acc3, &stg[wave][0], lane);   // y3acc = relu(y2)@W3

    // final: out = relu( relu(y3) . w4 + b4 )
    float p[4] = {0.f, 0.f, 0.f, 0.f};
    #pragma unroll
    for (int nt = 0; nt < 8; nt++) {
        int col = nt * 16 + c;
        float w = w4[col], bv = b3[col];
        #pragma unroll
        for (int r = 0; r < 4; r++) p[r] += fmaxf(acc3[nt][r] + bv, 0.f) * w;
    }
    #pragma unroll
    for (int r = 0; r < 4; r++) {
        p[r] += __shfl_xor(p[r], 1);
        p[r] += __shfl_xor(p[r], 2);
        p[r] += __shfl_xor(p[r], 4);
        p[r] += __shfl_xor(p[r], 8);
    }
    if (c == 0) {
        float bb = b4p[0];
        #pragma unroll
        for (int r = 0; r < 4; r++) {
            int row = base + g * 4 + r;
            if (row < M) out[row] = fmaxf(p[r] + bb, 0.f);
        }
    }
}

extern "C" void kernel_launch(void* const* d_in, const int* in_sizes, int n_in,
                              void* d_out, int out_size, void* d_ws, size_t ws_size,
                              hipStream_t stream)
{
    const float* x   = (const float*)d_in[0];
    const int*   ei  = (const int*)d_in[2];
    const int*   pei = (const int*)d_in[3];
    const float* W1  = (const float*)d_in[4];
    const float* b1  = (const float*)d_in[5];
    const float* W2  = (const float*)d_in[6];
    const float* b2  = (const float*)d_in[7];
    // d_in[8..11] = edge_mlp weights: dead w.r.t. output, skipped
    const float* pW1 = (const float*)d_in[12];
    const float* pb1 = (const float*)d_in[13];
    const float* pW2 = (const float*)d_in[14];
    const float* pb2 = (const float*)d_in[15];
    const float* pW3 = (const float*)d_in[16];
    const float* pb3 = (const float*)d_in[17];
    const float* pW4 = (const float*)d_in[18];
    const float* pb4 = (const float*)d_in[19];

    const int N  = in_sizes[0] / 128;
    const int E  = in_sizes[2] / 2;
    const int EP = in_sizes[3] / 2;
    const int Npad = (N + 255) & ~255;

    float*    ws     = (float*)d_ws;
    float*    dinv   = ws;                                  // Npad
    unsigned* bufA   = (unsigned*)(ws + Npad);              // N*128
    unsigned* bufB   = bufA + (size_t)N * 128;              // N*128
    int*      deg    = (int*)(bufB + (size_t)N * 128);      // Npad
    int*      rowptr = deg + Npad;                          // Npad
    int*      cursor = rowptr + Npad;                       // Npad
    int*      csr    = cursor + Npad;                       // E
    int*      bsum   = csr + E;                             // 512
    size_t wpOff = ((size_t)(bsum + 512) + 15) & ~(size_t)15;
    unsigned short* wp = (unsigned short*)wpOff;            // 6 x 32768 u16
    unsigned short* W1p  = wp;
    unsigned short* W2p  = wp + 32768;
    unsigned short* P1Ap = wp + 2 * 32768;
    unsigned short* P1Bp = wp + 3 * 32768;
    unsigned short* P2p  = wp + 4 * 32768;
    unsigned short* P3p  = wp + 5 * 32768;
    float* out = (float*)d_out;

    const int* esrc = ei;
    const int* edst = ei + E;
    const int* psrc = pei;
    const int* pdst = pei + EP;

    const int nb = (N + 255) / 256;
    const int gN = (N + 255) / 256;
    const int gE = (E + 255) / 256;
    const int gT = (N + 127) / 128;
    const int gP = (EP + 127) / 128;

    // ---- CSR build + dinv ----
    zero2_k<<<gN, 256, 0, stream>>>(deg, cursor, N);
    hist_k<<<gE, 256, 0, stream>>>(edst, deg, E);
    scan1_k<<<nb, 256, 0, stream>>>(deg, rowptr, bsum, dinv, N);
    scan2_k<<<1, 512, 0, stream>>>(bsum, nb);
    scan3_k<<<gN, 256, 0, stream>>>(rowptr, bsum, N);
    place_k<<<gE, 256, 0, stream>>>(esrc, edst, rowptr, cursor, csr, E);

    // ---- weight prep ----
    wprep6_k<<<dim3(64, 6), 256, 0, stream>>>(W1, W2, pW1, pW1 + 128 * 128, pW2, pW3, wp);

    // ---- layer 0: hp1 = dinv ⊙ (x@W1); x1r = relu(agg + b1) ----
    rowgemm_k<0><<<gT, 512, 0, stream>>>(x, W1p, dinv, bufA, N);
    gather2_k<<<(N + 7) / 8, 256, 0, stream>>>(bufA, dinv, rowptr, deg, csr, b1, bufB, N);

    // ---- layer 1 ----
    rowgemm_k<1><<<gT, 512, 0, stream>>>(bufB, W2p, dinv, bufA, N);
    gather2_k<<<(N + 7) / 8, 256, 0, stream>>>(bufA, dinv, rowptr, deg, csr, b2, bufB, N);

    // ---- fused predict MLP ----
    mlp_k<<<gP, 512, 0, stream>>>(bufB, psrc, pdst, P1Ap, P1Bp, pb1, P2p, pb2, P3p, pb3,
                                  pW4, pb4, out, EP);
}

// Round 5
// 339.546 us; speedup vs baseline: 7.4535x; 1.0591x over previous
//
#include <hip/hip_runtime.h>

typedef __attribute__((ext_vector_type(8))) short bf16x8;
typedef __attribute__((ext_vector_type(4))) float f32x4;

// ---- split-bf16 helpers: value v ~ hi + lo, packed as (hi16<<16)|lo16 ----
__device__ __forceinline__ unsigned bfr16(float x) {            // RNE fp32->bf16 bits
    unsigned u = __float_as_uint(x);
    return (u + 0x7fffu + ((u >> 16) & 1u)) >> 16;
}
__device__ __forceinline__ unsigned pack_bf2(float v) {
    unsigned hr = bfr16(v);
    float lof = v - __uint_as_float(hr << 16);
    unsigned lr = bfr16(lof);
    return (hr << 16) | (lr & 0xffffu);
}
__device__ __forceinline__ float dec_bf2(unsigned p) {
    return __uint_as_float(p & 0xffff0000u) + __uint_as_float(p << 16);
}

union U8 { bf16x8 v; unsigned u[4]; };

// activation B-fragment from 8 consecutive packed u32 (sample = lane&15, k-slice = (lane>>4)*8)
__device__ __forceinline__ void frag_from_packed(const unsigned* ap, bf16x8& hi, bf16x8& lo) {
    uint4 u0 = *(const uint4*)ap;
    uint4 u1 = *(const uint4*)(ap + 4);
    U8 H, L;
    H.u[0] = __builtin_amdgcn_perm(u0.y, u0.x, 0x07060302u);
    H.u[1] = __builtin_amdgcn_perm(u0.w, u0.z, 0x07060302u);
    H.u[2] = __builtin_amdgcn_perm(u1.y, u1.x, 0x07060302u);
    H.u[3] = __builtin_amdgcn_perm(u1.w, u1.z, 0x07060302u);
    L.u[0] = __builtin_amdgcn_perm(u0.y, u0.x, 0x05040100u);
    L.u[1] = __builtin_amdgcn_perm(u0.w, u0.z, 0x05040100u);
    L.u[2] = __builtin_amdgcn_perm(u1.y, u1.x, 0x05040100u);
    L.u[3] = __builtin_amdgcn_perm(u1.w, u1.z, 0x05040100u);
    hi = H.v; lo = L.v;
}

__device__ __forceinline__ void frag_from_f32(const float* fp, bf16x8& hi, bf16x8& lo) {
    float4 f0 = *(const float4*)fp;
    float4 f1 = *(const float4*)(fp + 4);
    float fv[8] = {f0.x, f0.y, f0.z, f0.w, f1.x, f1.y, f1.z, f1.w};
    U8 H, L;
    #pragma unroll
    for (int p = 0; p < 4; p++) {
        float a = fv[2 * p], b = fv[2 * p + 1];
        unsigned ra = bfr16(a), rb = bfr16(b);
        H.u[p] = ra | (rb << 16);
        float la = a - __uint_as_float(ra << 16);
        float lb = b - __uint_as_float(rb << 16);
        L.u[p] = bfr16(la) | (bfr16(lb) << 16);
    }
    hi = H.v; lo = L.v;
}

// weight A-operand fragment pair (hi plane at 0, lo plane at +16384 u16)
__device__ __forceinline__ void wfrag(const unsigned short* Wp, int f, int lane,
                                      bf16x8& whi, bf16x8& wlo) {
    whi = *(const bf16x8*)(Wp + f * 512 + lane * 8);
    wlo = *(const bf16x8*)(Wp + 16384 + f * 512 + lane * 8);
}

#define MFMA3(accv, whi, wlo, yhi, ylo)                                              \
    accv = __builtin_amdgcn_mfma_f32_16x16x32_bf16(whi, yhi, accv, 0, 0, 0);         \
    accv = __builtin_amdgcn_mfma_f32_16x16x32_bf16(whi, ylo, accv, 0, 0, 0);         \
    accv = __builtin_amdgcn_mfma_f32_16x16x32_bf16(wlo, yhi, accv, 0, 0, 0);

// slot->true-channel map: chan(nt, rho=4g+r) = 32*(nt>>1) + 8*g + 4*(nt&1) + r
// self-consistent: B-frag built as acc[2kt+(j>>2)][j&3] reads true channel kt*32+g*8+j.

// layer transition entirely in registers: y(kt) fragment from acc + bias (+relu)
__device__ __forceinline__ void trans_frag(const f32x4* acc, const float4* bv, int kt,
                                           bf16x8& yh, bf16x8& yl) {
    const int n0 = 2 * kt, n1 = n0 + 1;
    float v0 = fmaxf(acc[n0][0] + bv[n0].x, 0.f);
    float v1 = fmaxf(acc[n0][1] + bv[n0].y, 0.f);
    float v2 = fmaxf(acc[n0][2] + bv[n0].z, 0.f);
    float v3 = fmaxf(acc[n0][3] + bv[n0].w, 0.f);
    float v4 = fmaxf(acc[n1][0] + bv[n1].x, 0.f);
    float v5 = fmaxf(acc[n1][1] + bv[n1].y, 0.f);
    float v6 = fmaxf(acc[n1][2] + bv[n1].z, 0.f);
    float v7 = fmaxf(acc[n1][3] + bv[n1].w, 0.f);
    U8 H, L;
    unsigned ra, rb;
    ra = bfr16(v0); rb = bfr16(v1);
    H.u[0] = ra | (rb << 16);
    L.u[0] = bfr16(v0 - __uint_as_float(ra << 16)) | (bfr16(v1 - __uint_as_float(rb << 16)) << 16);
    ra = bfr16(v2); rb = bfr16(v3);
    H.u[1] = ra | (rb << 16);
    L.u[1] = bfr16(v2 - __uint_as_float(ra << 16)) | (bfr16(v3 - __uint_as_float(rb << 16)) << 16);
    ra = bfr16(v4); rb = bfr16(v5);
    H.u[2] = ra | (rb << 16);
    L.u[2] = bfr16(v4 - __uint_as_float(ra << 16)) | (bfr16(v5 - __uint_as_float(rb << 16)) << 16);
    ra = bfr16(v6); rb = bfr16(v7);
    H.u[3] = ra | (rb << 16);
    L.u[3] = bfr16(v6 - __uint_as_float(ra << 16)) | (bfr16(v7 - __uint_as_float(rb << 16)) << 16);
    yh = H.v; yl = L.v;
}

// ---------------- CSR build ----------------

__global__ void zero2_k(int* __restrict__ a, int* __restrict__ b, int n) {
    int i = blockIdx.x * blockDim.x + threadIdx.x;
    if (i < n) { a[i] = 0; b[i] = 0; }
}

__global__ void hist_k(const int* __restrict__ dst, int* __restrict__ deg, int E) {
    int e = blockIdx.x * blockDim.x + threadIdx.x;
    if (e < E) atomicAdd(&deg[dst[e]], 1);
}

__global__ void scan1_k(const int* __restrict__ deg, int* __restrict__ rowptr,
                        int* __restrict__ bsum, float* __restrict__ dinv, int n) {
    __shared__ int s[256];
    int tid = threadIdx.x;
    int i = blockIdx.x * 256 + tid;
    int v = (i < n) ? deg[i] : 0;
    s[tid] = v;
    __syncthreads();
    #pragma unroll
    for (int off = 1; off < 256; off <<= 1) {
        int t = (tid >= off) ? s[tid - off] : 0;
        __syncthreads();
        s[tid] += t;
        __syncthreads();
    }
    if (i < n) {
        rowptr[i] = s[tid] - v;
        dinv[i] = rsqrtf((float)(v + 1));
    }
    if (tid == 255) bsum[blockIdx.x] = s[255];
}

__global__ void scan2_k(int* __restrict__ bsum, int nb) {
    __shared__ int s[512];
    int tid = threadIdx.x;
    int v = (tid < nb) ? bsum[tid] : 0;
    s[tid] = v;
    __syncthreads();
    #pragma unroll
    for (int off = 1; off < 512; off <<= 1) {
        int t = (tid >= off) ? s[tid - off] : 0;
        __syncthreads();
        s[tid] += t;
        __syncthreads();
    }
    if (tid < nb) bsum[tid] = s[tid] - v;
}

__global__ void scan3_k(int* __restrict__ rowptr, const int* __restrict__ bsum, int n) {
    int i = blockIdx.x * blockDim.x + threadIdx.x;
    if (i < n) rowptr[i] += bsum[i >> 8];
}

__global__ void place_k(const int* __restrict__ src, const int* __restrict__ dst,
                        const int* __restrict__ rowptr, int* __restrict__ cursor,
                        int* __restrict__ csr, int E) {
    int e = blockIdx.x * blockDim.x + threadIdx.x;
    if (e < E) {
        int d = dst[e];
        int pos = rowptr[d] + atomicAdd(&cursor[d], 1);
        csr[pos] = src[e];
    }
}

// ---- weight prep: W[k][c] -> A-operand frag (slot-permuted columns) ----
// A-tile nt(c) = ((c>>5)<<1)|((c>>2)&1), row rho(c) = (((c>>3)&3)<<2)|(c&3),
// lane = ((k>>3)&3)<<4 | rho, elem j = k&7, frag f = (k>>5)*8 + nt.
__global__ void wprep6_k(const float* __restrict__ s0, const float* __restrict__ s1,
                         const float* __restrict__ s2, const float* __restrict__ s3,
                         const float* __restrict__ s4, const float* __restrict__ s5,
                         unsigned short* __restrict__ dstBase) {
    const float* W;
    switch (blockIdx.y) {
        case 0: W = s0; break; case 1: W = s1; break; case 2: W = s2; break;
        case 3: W = s3; break; case 4: W = s4; break; default: W = s5; break;
    }
    unsigned short* out = dstBase + (size_t)blockIdx.y * 32768;
    int idx = blockIdx.x * 256 + threadIdx.x;
    if (idx >= 16384) return;
    int k = idx >> 7, c = idx & 127;
    float v = W[k * 128 + c];
    unsigned hr = bfr16(v);
    float lof = v - __uint_as_float(hr << 16);
    unsigned lr = bfr16(lof);
    int kt = k >> 5, gk = (k >> 3) & 3, j = k & 7;
    int nt = ((c >> 5) << 1) | ((c >> 2) & 1);
    int rho = (((c >> 3) & 3) << 2) | (c & 3);
    int lane = (gk << 4) | rho;
    int pos = (kt * 8 + nt) * 512 + lane * 8 + j;
    out[pos] = (unsigned short)hr;
    out[16384 + pos] = (unsigned short)lr;
}

// ---- gather aggregate: out[i] = relu(bias + dinv[i]*(hp[i] + sum_in hp[s])), packed.
// 2 nodes per wave; 32 lanes x uint4 per node; 4-way unrolled neighbor loop.
__global__ __launch_bounds__(256)
void gather2_k(const unsigned* __restrict__ hp, const float* __restrict__ dinv,
               const int* __restrict__ rowptr, const int* __restrict__ deg,
               const int* __restrict__ csr, const float* __restrict__ bias,
               unsigned* __restrict__ out, int N)
{
    int tid = threadIdx.x;
    int lane = tid & 63;
    int sub = lane >> 5;
    int i = blockIdx.x * 8 + (tid >> 6) * 2 + sub;
    if (i >= N) return;
    int c4 = (lane & 31) * 4;
    uint4 p = *(const uint4*)(hp + (size_t)i * 128 + c4);
    float a0 = dec_bf2(p.x), a1 = dec_bf2(p.y), a2 = dec_bf2(p.z), a3 = dec_bf2(p.w);
    int beg = rowptr[i], dg = deg[i];
    int j = 0;
    for (; j + 3 < dg; j += 4) {
        int s0 = csr[beg + j], s1 = csr[beg + j + 1];
        int s2 = csr[beg + j + 2], s3 = csr[beg + j + 3];
        uint4 q0 = *(const uint4*)(hp + (size_t)s0 * 128 + c4);
        uint4 q1 = *(const uint4*)(hp + (size_t)s1 * 128 + c4);
        uint4 q2 = *(const uint4*)(hp + (size_t)s2 * 128 + c4);
        uint4 q3 = *(const uint4*)(hp + (size_t)s3 * 128 + c4);
        a0 += (dec_bf2(q0.x) + dec_bf2(q1.x)) + (dec_bf2(q2.x) + dec_bf2(q3.x));
        a1 += (dec_bf2(q0.y) + dec_bf2(q1.y)) + (dec_bf2(q2.y) + dec_bf2(q3.y));
        a2 += (dec_bf2(q0.z) + dec_bf2(q1.z)) + (dec_bf2(q2.z) + dec_bf2(q3.z));
        a3 += (dec_bf2(q0.w) + dec_bf2(q1.w)) + (dec_bf2(q2.w) + dec_bf2(q3.w));
    }
    for (; j < dg; j++) {
        int s0 = csr[beg + j];
        uint4 q0 = *(const uint4*)(hp + (size_t)s0 * 128 + c4);
        a0 += dec_bf2(q0.x); a1 += dec_bf2(q0.y); a2 += dec_bf2(q0.z); a3 += dec_bf2(q0.w);
    }
    float di = dinv[i];
    float4 bv = *(const float4*)(bias + c4);
    uint4 o;
    o.x = pack_bf2(fmaxf(bv.x + di * a0, 0.f));
    o.y = pack_bf2(fmaxf(bv.y + di * a1, 0.f));
    o.z = pack_bf2(fmaxf(bv.z + di * a2, 0.f));
    o.w = pack_bf2(fmaxf(bv.w + di * a3, 0.f));
    *(uint4*)(out + (size_t)i * 128 + c4) = o;
}

// ---- layer GEMM: C = dinv-row-scaled (A @ W), packed out, natural channel addresses.
// Activation = B operand (sample = lane&15); weight = A operand (slot-permuted).
template<int AMODE>   // 0: A fp32 ; 1: A packed split-bf16
__global__ __launch_bounds__(512)
void rowgemm_k(const void* __restrict__ Asrc, const unsigned short* __restrict__ Wp,
               const float* __restrict__ rowScale, unsigned* __restrict__ Cout, int M)
{
    const int t = threadIdx.x, lane = t & 63, wave = t >> 6;
    const int base = blockIdx.x * 128 + wave * 16;
    const int s = lane & 15, g = lane >> 4, kg = g * 8;
    const int arow = base + s;
    const int rowc = (arow < M) ? arow : (M - 1);

    f32x4 acc[8];
    #pragma unroll
    for (int nt = 0; nt < 8; nt++) acc[nt] = (f32x4){0.f, 0.f, 0.f, 0.f};

    #pragma unroll
    for (int kt = 0; kt < 4; kt++) {
        bf16x8 yhi, ylo;
        if (AMODE == 1)
            frag_from_packed((const unsigned*)Asrc + (size_t)rowc * 128 + kt * 32 + kg, yhi, ylo);
        else
            frag_from_f32((const float*)Asrc + (size_t)rowc * 128 + kt * 32 + kg, yhi, ylo);
        #pragma unroll
        for (int nt = 0; nt < 8; nt++) {
            bf16x8 whi, wlo;
            wfrag(Wp, kt * 8 + nt, lane, whi, wlo);
            MFMA3(acc[nt], whi, wlo, yhi, ylo);
        }
    }

    if (arow < M) {
        float sc = rowScale[arow];
        #pragma unroll
        for (int nt = 0; nt < 8; nt++) {
            int cbase = 32 * (nt >> 1) + 8 * g + 4 * (nt & 1);
            uint4 o;
            o.x = pack_bf2(acc[nt][0] * sc);
            o.y = pack_bf2(acc[nt][1] * sc);
            o.z = pack_bf2(acc[nt][2] * sc);
            o.w = pack_bf2(acc[nt][3] * sc);
            *(uint4*)(Cout + (size_t)arow * 128 + cbase) = o;
        }
    }
}

// ---- fused predict MLP: gather xi/xj -> y1 -> y2 -> y3 -> dot -> out. Zero LDS. ----
__global__ __launch_bounds__(512)
void mlp_k(const unsigned* __restrict__ X, const int* __restrict__ psrc, const int* __restrict__ pdst,
           const unsigned short* __restrict__ W1a, const unsigned short* __restrict__ W1b,
           const float* __restrict__ b1, const unsigned short* __restrict__ W2p,
           const float* __restrict__ b2, const unsigned short* __restrict__ W3p,
           const float* __restrict__ b3, const float* __restrict__ w4,
           const float* __restrict__ b4p, float* __restrict__ out, int M)
{
    const int t = threadIdx.x, lane = t & 63, wave = t >> 6;
    const int base = blockIdx.x * 128 + wave * 16;
    const int s = lane & 15, g = lane >> 4, kg = g * 8;
    const int arow = base + s;
    const int rowc = (arow < M) ? arow : (M - 1);
    const int si = psrc[rowc], sj = pdst[rowc];

    // load xi/xj B-fragments for all kt upfront (coalesced 32B/lane slices)
    bf16x8 xih[4], xil[4], xjh[4], xjl[4];
    #pragma unroll
    for (int kt = 0; kt < 4; kt++)
        frag_from_packed(X + (size_t)si * 128 + kt * 32 + kg, xih[kt], xil[kt]);
    #pragma unroll
    for (int kt = 0; kt < 4; kt++)
        frag_from_packed(X + (size_t)sj * 128 + kt * 32 + kg, xjh[kt], xjl[kt]);

    // ---- layer 1: acc1 = W1a^T·xi + W1b^T·xj (slot-permuted oc) ----
    f32x4 acc1[8];
    #pragma unroll
    for (int nt = 0; nt < 8; nt++) acc1[nt] = (f32x4){0.f, 0.f, 0.f, 0.f};
    #pragma unroll
    for (int kt = 0; kt < 4; kt++) {
        #pragma unroll
        for (int nt = 0; nt < 8; nt++) {
            bf16x8 whi, wlo;
            wfrag(W1a, kt * 8 + nt, lane, whi, wlo);
            MFMA3(acc1[nt], whi, wlo, xih[kt], xil[kt]);
            wfrag(W1b, kt * 8 + nt, lane, whi, wlo);
            MFMA3(acc1[nt], whi, wlo, xjh[kt], xjl[kt]);
        }
    }
    __syncthreads();   // keep waves in lockstep for L1 weight reuse

    // ---- layer 2 ----
    float4 b1v[8];
    #pragma unroll
    for (int nt = 0; nt < 8; nt++)
        b1v[nt] = *(const float4*)(b1 + 32 * (nt >> 1) + 8 * g + 4 * (nt & 1));
    f32x4 acc2[8];
    #pragma unroll
    for (int nt = 0; nt < 8; nt++) acc2[nt] = (f32x4){0.f, 0.f, 0.f, 0.f};
    #pragma unroll
    for (int kt = 0; kt < 4; kt++) {
        bf16x8 yh, yl;
        trans_frag(acc1, b1v, kt, yh, yl);
        #pragma unroll
        for (int nt = 0; nt < 8; nt++) {
            bf16x8 whi, wlo;
            wfrag(W2p, kt * 8 + nt, lane, whi, wlo);
            MFMA3(acc2[nt], whi, wlo, yh, yl);
        }
    }
    __syncthreads();

    // ---- layer 3 ----
    float4 b2v[8];
    #pragma unroll
    for (int nt = 0; nt < 8; nt++)
        b2v[nt] = *(const float4*)(b2 + 32 * (nt >> 1) + 8 * g + 4 * (nt & 1));
    f32x4 acc3[8];
    #pragma unroll
    for (int nt = 0; nt < 8; nt++) acc3[nt] = (f32x4){0.f, 0.f, 0.f, 0.f};
    #pragma unroll
    for (int kt = 0; kt < 4; kt++) {
        bf16x8 yh, yl;
        trans_frag(acc2, b2v, kt, yh, yl);
        #pragma unroll
        for (int nt = 0; nt < 8; nt++) {
            bf16x8 whi, wlo;
            wfrag(W3p, kt * 8 + nt, lane, whi, wlo);
            MFMA3(acc3[nt], whi, wlo, yh, yl);
        }
    }

    // ---- final: out[s] = relu( sum_c relu(y3[c]) * w4[c] + b4 ) ----
    float4 b3v[8], w4v[8];
    #pragma unroll
    for (int nt = 0; nt < 8; nt++) {
        int off = 32 * (nt >> 1) + 8 * g + 4 * (nt & 1);
        b3v[nt] = *(const float4*)(b3 + off);
        w4v[nt] = *(const float4*)(w4 + off);
    }
    float p = 0.f;
    #pragma unroll
    for (int nt = 0; nt < 8; nt++) {
        p += fmaxf(acc3[nt][0] + b3v[nt].x, 0.f) * w4v[nt].x;
        p += fmaxf(acc3[nt][1] + b3v[nt].y, 0.f) * w4v[nt].y;
        p += fmaxf(acc3[nt][2] + b3v[nt].z, 0.f) * w4v[nt].z;
        p += fmaxf(acc3[nt][3] + b3v[nt].w, 0.f) * w4v[nt].w;
    }
    p += __shfl_xor(p, 16, 64);
    p += __shfl_xor(p, 32, 64);
    if (g == 0 && arow < M) out[arow] = fmaxf(p + b4p[0], 0.f);
}

extern "C" void kernel_launch(void* const* d_in, const int* in_sizes, int n_in,
                              void* d_out, int out_size, void* d_ws, size_t ws_size,
                              hipStream_t stream)
{
    const float* x   = (const float*)d_in[0];
    const int*   ei  = (const int*)d_in[2];
    const int*   pei = (const int*)d_in[3];
    const float* W1  = (const float*)d_in[4];
    const float* b1  = (const float*)d_in[5];
    const float* W2  = (const float*)d_in[6];
    const float* b2  = (const float*)d_in[7];
    // d_in[8..11] = edge_mlp weights: dead w.r.t. output, skipped
    const float* pW1 = (const float*)d_in[12];
    const float* pb1 = (const float*)d_in[13];
    const float* pW2 = (const float*)d_in[14];
    const float* pb2 = (const float*)d_in[15];
    const float* pW3 = (const float*)d_in[16];
    const float* pb3 = (const float*)d_in[17];
    const float* pW4 = (const float*)d_in[18];
    const float* pb4 = (const float*)d_in[19];

    const int N  = in_sizes[0] / 128;
    const int E  = in_sizes[2] / 2;
    const int EP = in_sizes[3] / 2;
    const int Npad = (N + 255) & ~255;

    float*    ws     = (float*)d_ws;
    float*    dinv   = ws;                                  // Npad
    unsigned* bufA   = (unsigned*)(ws + Npad);              // N*128
    unsigned* bufB   = bufA + (size_t)N * 128;              // N*128
    int*      deg    = (int*)(bufB + (size_t)N * 128);      // Npad
    int*      rowptr = deg + Npad;                          // Npad
    int*      cursor = rowptr + Npad;                       // Npad
    int*      csr    = cursor + Npad;                       // E
    int*      bsum   = csr + E;                             // 512
    size_t wpOff = ((size_t)(bsum + 512) + 15) & ~(size_t)15;
    unsigned short* wp = (unsigned short*)wpOff;            // 6 x 32768 u16
    unsigned short* W1p  = wp;
    unsigned short* W2p  = wp + 32768;
    unsigned short* P1Ap = wp + 2 * 32768;
    unsigned short* P1Bp = wp + 3 * 32768;
    unsigned short* P2p  = wp + 4 * 32768;
    unsigned short* P3p  = wp + 5 * 32768;
    float* out = (float*)d_out;

    const int* esrc = ei;
    const int* edst = ei + E;
    const int* psrc = pei;
    const int* pdst = pei + EP;

    const int nb = (N + 255) / 256;
    const int gN = (N + 255) / 256;
    const int gE = (E + 255) / 256;
    const int gT = (N + 127) / 128;
    const int gP = (EP + 127) / 128;

    // ---- CSR build + dinv ----
    zero2_k<<<gN, 256, 0, stream>>>(deg, cursor, N);
    hist_k<<<gE, 256, 0, stream>>>(edst, deg, E);
    scan1_k<<<nb, 256, 0, stream>>>(deg, rowptr, bsum, dinv, N);
    scan2_k<<<1, 512, 0, stream>>>(bsum, nb);
    scan3_k<<<gN, 256, 0, stream>>>(rowptr, bsum, N);
    place_k<<<gE, 256, 0, stream>>>(esrc, edst, rowptr, cursor, csr, E);

    // ---- weight prep ----
    wprep6_k<<<dim3(64, 6), 256, 0, stream>>>(W1, W2, pW1, pW1 + 128 * 128, pW2, pW3, wp);

    // ---- layer 0: hp1 = dinv ⊙ (x@W1); x1r = relu(agg + b1) ----
    rowgemm_k<0><<<gT, 512, 0, stream>>>(x, W1p, dinv, bufA, N);
    gather2_k<<<(N + 7) / 8, 256, 0, stream>>>(bufA, dinv, rowptr, deg, csr, b1, bufB, N);

    // ---- layer 1 ----
    rowgemm_k<1><<<gT, 512, 0, stream>>>(bufB, W2p, dinv, bufA, N);
    gather2_k<<<(N + 7) / 8, 256, 0, stream>>>(bufA, dinv, rowptr, deg, csr, b2, bufB, N);

    // ---- fused predict MLP ----
    mlp_k<<<gP, 512, 0, stream>>>(bufB, psrc, pdst, P1Ap, P1Bp, pb1, P2p, pb2, P3p, pb3,
                                  pW4, pb4, out, EP);
}